// Round 5
// baseline (165.315 us; speedup 1.0000x reference)
//
#include <hip/hip_runtime.h>
#include <math.h>

#define EPSF 1e-12f
#define ATT_NORM_F 4.0f
#define H_DIM 8
#define C_DIM 16
#define N_NODES 100000

typedef float v4f __attribute__((ext_vector_type(4)));

// ---------------------------------------------------------------------------
// Zero the seg table.
// ---------------------------------------------------------------------------
__global__ __launch_bounds__(256) void lip_zero(unsigned* __restrict__ p, int n)
{
    int i = blockIdx.x * 256 + threadIdx.x;
    if (i < n) p[i] = 0u;
}

// ---------------------------------------------------------------------------
// Pass 1a: PURE streaming norms. No atomics, no gathers — just read 512 MB of
// x at full rate and write 32 MB of norm_x (regular store -> stays in L2/L3
// for the two downstream readers).
// 4 lanes per (e,h) row; each wave instruction covers 1 KB contiguous.
// ---------------------------------------------------------------------------
__global__ __launch_bounds__(256) void lip_norm(
    const float* __restrict__ x, float* __restrict__ norm_x, int total /*rows*4*/)
{
    const int stride = gridDim.x * 256;
    const int s0 = blockIdx.x * 256 + threadIdx.x;
    const int lane = s0 & 3;                 // stride % 4 == 0 -> constant
    const v4f* x4 = (const v4f*)x;

    #pragma unroll 8
    for (int s = s0; s < total; s += stride) {
        v4f v = __builtin_nontemporal_load(&x4[s]);
        float sum = v.x * v.x + v.y * v.y + v.z * v.z + v.w * v.w;
        sum += __shfl_xor(sum, 1);
        sum += __shfl_xor(sum, 2);
        if (lane == 0) {
            // 16 lanes/wave x 4B consecutive = one full 64B sector
            norm_x[s >> 2] = sum;
        }
    }
}

// ---------------------------------------------------------------------------
// Pass 1b: the scatter-max. Reads norm_x (L2/L3-warm) + index, fires 8M
// fire-and-forget atomicMax RMWs. No dependent use of the atomics -> the
// wave never waits on them until kernel end; deep unroll keeps many in
// flight.
// ---------------------------------------------------------------------------
__global__ __launch_bounds__(256) void lip_scatter(
    const float* __restrict__ norm_x, const int* __restrict__ index,
    unsigned int* __restrict__ seg, int rows)
{
    const int stride = gridDim.x * 256;
    #pragma unroll 8
    for (int r = blockIdx.x * 256 + threadIdx.x; r < rows; r += stride) {
        float s = norm_x[r];                  // coalesced, cache-warm
        int e = r >> 3;
        int h = r & 7;
        // s >= 0: float bits monotone under unsigned max
        atomicMax(&seg[(size_t)index[e] * H_DIM + h], __float_as_uint(s));
    }
}

// ---------------------------------------------------------------------------
// Pass 2: out = alpha / (natt * sqrt(seg[idx] + norm_x) + eps)
// One thread per 4 heads (float4). seg gathers are cache-resident.
// ---------------------------------------------------------------------------
__global__ __launch_bounds__(256) void lip_pass2(
    const float* __restrict__ norm_x, const float* __restrict__ alpha,
    const int* __restrict__ index, const unsigned int* __restrict__ seg,
    const float* __restrict__ att_l, const float* __restrict__ att_r,
    float* __restrict__ out, int total)   // total = E*2
{
    __shared__ float s_natt[H_DIM];
    int t = threadIdx.x;
    if (t < H_DIM) {
        float s = 0.f;
        #pragma unroll
        for (int c = 0; c < C_DIM; ++c) {
            float l = att_l[t * C_DIM + c];
            float r = att_r[t * C_DIM + c];
            s += l * l + r * r;
        }
        s_natt[t] = ATT_NORM_F * sqrtf(s);
    }
    __syncthreads();

    const int stride = gridDim.x * 256;
    const v4f* nx4 = (const v4f*)norm_x;
    const v4f* al4 = (const v4f*)alpha;
    const v4f* sg4 = (const v4f*)seg;       // bits are non-negative floats
    v4f* out4 = (v4f*)out;

    #pragma unroll 4
    for (int tid = blockIdx.x * 256 + t; tid < total; tid += stride) {
        int e    = tid >> 1;
        int half = tid & 1;
        int idx  = index[e];

        v4f nx = nx4[tid];                               // cache-warm
        v4f al = __builtin_nontemporal_load(&al4[tid]);  // cold stream
        v4f sg = sg4[(size_t)idx * 2 + half];            // cached gather

        int h0 = half * 4;
        v4f o;
        o.x = al.x / (s_natt[h0 + 0] * sqrtf(sg.x + nx.x) + EPSF);
        o.y = al.y / (s_natt[h0 + 1] * sqrtf(sg.y + nx.y) + EPSF);
        o.z = al.z / (s_natt[h0 + 2] * sqrtf(sg.z + nx.z) + EPSF);
        o.w = al.w / (s_natt[h0 + 3] * sqrtf(sg.w + nx.w) + EPSF);
        __builtin_nontemporal_store(o, &out4[tid]);
    }
}

// ---------------------------------------------------------------------------
// Fallback pass 2 (no norm_x buffer): recompute norm from x, scalar path.
// ---------------------------------------------------------------------------
__global__ __launch_bounds__(256) void lip_pass2_recompute(
    const float* __restrict__ x, const float* __restrict__ alpha,
    const int* __restrict__ index, const unsigned int* __restrict__ seg,
    const float* __restrict__ att_l, const float* __restrict__ att_r,
    float* __restrict__ out, int rows)
{
    __shared__ float s_natt[H_DIM];
    int t = threadIdx.x;
    if (t < H_DIM) {
        float s = 0.f;
        #pragma unroll
        for (int c = 0; c < C_DIM; ++c) {
            float l = att_l[t * C_DIM + c];
            float r = att_r[t * C_DIM + c];
            s += l * l + r * r;
        }
        s_natt[t] = ATT_NORM_F * sqrtf(s);
    }
    __syncthreads();

    int r = blockIdx.x * blockDim.x + t;
    if (r >= rows) return;

    const float4* x4 = (const float4*)x;
    float s = 0.f;
    #pragma unroll
    for (int q = 0; q < 4; ++q) {
        float4 v = x4[(size_t)r * 4 + q];
        s += v.x * v.x + v.y * v.y + v.z * v.z + v.w * v.w;
    }
    int e = r >> 3;
    int h = r & 7;
    float sg = __uint_as_float(seg[(size_t)index[e] * H_DIM + h]);
    out[r] = alpha[r] / (s_natt[h] * sqrtf(sg + s) + EPSF);
}

// Pass 1 merged fallback (used only if ws can't hold norm_x).
__global__ __launch_bounds__(256) void lip_pass1_merged(
    const float* __restrict__ x, const int* __restrict__ index,
    unsigned int* __restrict__ seg, int total /*rows*4*/)
{
    const int stride = gridDim.x * 256;
    const int s0 = blockIdx.x * 256 + threadIdx.x;
    const int lane = s0 & 3;
    const v4f* x4 = (const v4f*)x;
    #pragma unroll 4
    for (int s = s0; s < total; s += stride) {
        v4f v = __builtin_nontemporal_load(&x4[s]);
        float sum = v.x * v.x + v.y * v.y + v.z * v.z + v.w * v.w;
        sum += __shfl_xor(sum, 1);
        sum += __shfl_xor(sum, 2);
        if (lane == 0) {
            int r = s >> 2;
            int e = r >> 3, h = r & 7;
            atomicMax(&seg[(size_t)index[e] * H_DIM + h], __float_as_uint(sum));
        }
    }
}

extern "C" void kernel_launch(void* const* d_in, const int* in_sizes, int n_in,
                              void* d_out, int out_size, void* d_ws, size_t ws_size,
                              hipStream_t stream) {
    const float* x     = (const float*)d_in[0];
    const float* att_l = (const float*)d_in[1];
    const float* att_r = (const float*)d_in[2];
    const float* alpha = (const float*)d_in[3];
    const int*   index = (const int*)d_in[4];

    const int E    = in_sizes[4];
    const int rows = E * H_DIM;

    const int seg_words = N_NODES * H_DIM;        // 800000 = 3.2 MB
    size_t seg_pad = ((size_t)seg_words * 4 + 255) / 256 * 256;
    size_t need    = seg_pad + (size_t)rows * sizeof(float);

    unsigned* seg = (unsigned*)d_ws;
    lip_zero<<<(seg_words + 255) / 256, 256, 0, stream>>>(seg, seg_words);

    if (ws_size >= need) {
        float* norm_x = (float*)((char*)d_ws + seg_pad);
        lip_norm<<<2048, 256, 0, stream>>>(x, norm_x, rows * 4);
        lip_scatter<<<2048, 256, 0, stream>>>(norm_x, index, seg, rows);
        lip_pass2<<<2048, 256, 0, stream>>>(
            norm_x, alpha, index, seg, att_l, att_r, (float*)d_out, E * 2);
    } else {
        lip_pass1_merged<<<2048, 256, 0, stream>>>(x, index, seg, rows * 4);
        lip_pass2_recompute<<<(rows + 255) / 256, 256, 0, stream>>>(
            x, alpha, index, seg, att_l, att_r, (float*)d_out, rows);
    }
}